// Round 8
// baseline (109.570 us; speedup 1.0000x reference)
//
#include <hip/hip_runtime.h>
#include <stdint.h>
#include <stddef.h>

// Problem constants (fixed by the reference).
#define BSZ  256
#define NSZ  4096
#define CIN  8
#define KNB  9
#define DOUT 8
#define NSUB 2

typedef __fp16   fh2  __attribute__((ext_vector_type(2)));
typedef __fp16   v8fh __attribute__((ext_vector_type(8)));   // MFMA f16 A/B frag (4 VGPRs)
typedef float    f4   __attribute__((ext_vector_type(4)));
typedef uint32_t u32x4 __attribute__((ext_vector_type(4)));

#define BTAB_U32 (NSUB * 3 * 64 * 4)          // 1536 u32 = 6 KiB
#define BOFF     ((NSZ + 1) * 4)              // btab offset (u32 units) in LDS

static __device__ __forceinline__ uint32_t pk_f16(float a, float b) {
    fh2 h = __builtin_amdgcn_cvt_pkrtz(a, b);   // v_cvt_pkrtz_f16_f32
    return __builtin_bit_cast(uint32_t, h);
}

// grid = 256: one block per b; each block stages x[b] ONCE and computes all 4096 n.
// 16 waves x 16 tiles x 16 n. All nbh/sub metadata prefetched to VGPRs before the
// barrier (overlaps staging HBM); compute loop is pure LDS-gather + MFMA + store.
// 1 block/CU (16 waves = 4/SIMD) -> VGPR budget 128.
__global__ __launch_bounds__(1024, 4) void latconv_kernel(
    const float* __restrict__ x, const int* __restrict__ nbh,
    const int* __restrict__ sub, const float* __restrict__ w,
    const float* __restrict__ bias, float* __restrict__ out)
{
    __shared__ __align__(16) uint32_t xl[BOFF + BTAB_U32];   // 65552 + 6144 B

    const int b = blockIdx.x;
    const int t = threadIdx.x;
    const float* xb = x + (size_t)b * (CIN * NSZ);

    // ---- build B-fragment table in LDS ----
    // entry t2 (0..383): lane = t2&63, s = (t2>>6)%3, sg = t2/192;
    // col d = lane&15, kslot = s*4 + (lane>>4); elem pair cp = channels (2cp, 2cp+1).
    if (t < NSUB * 3 * 64) {
        const int lane2 = t & 63, s = (t >> 6) % 3, sg = t / 192;
        const int g2 = lane2 >> 4, d2 = lane2 & 15, ks = s * 4 + g2;
        u32x4 row;
        #pragma unroll
        for (int cp = 0; cp < 4; ++cp) {
            float v0 = 0.f, v1 = 0.f;
            if (d2 < DOUT && ks < KNB) {
                v0 = w[((sg * CIN + 2 * cp    ) * KNB + ks) * DOUT + d2];
                v1 = w[((sg * CIN + 2 * cp + 1) * KNB + ks) * DOUT + d2];
            }
            row[cp] = pk_f16(v0, v1);
        }
        *reinterpret_cast<u32x4*>(&xl[BOFF + 4 * (size_t)t]) = row;
    }

    // ---- stage x[b] -> LDS (fp32 -> packed fp16, transpose to [j][c]) ----
    {
        const int j0 = 4 * t;
        f4 v[CIN];
        #pragma unroll
        for (int c = 0; c < CIN; ++c)
            v[c] = *reinterpret_cast<const f4*>(xb + c * NSZ + j0);   // coalesced 16B
        #pragma unroll
        for (int jj = 0; jj < 4; ++jj) {
            u32x4 row;
            #pragma unroll
            for (int cp = 0; cp < 4; ++cp)
                row[cp] = pk_f16(v[2 * cp][jj], v[2 * cp + 1][jj]);
            *reinterpret_cast<u32x4*>(&xl[(size_t)(j0 + jj) * 4]) = row;  // ds_write_b128
        }
    }
    if (t == 0) {   // zero sentinel row for padded k-slots
        u32x4 z = { 0, 0, 0, 0 };
        *reinterpret_cast<u32x4*>(&xl[(size_t)NSZ * 4]) = z;
    }

    const int lane = t & 63, wv = t >> 6;
    const int g = lane >> 4, r = lane & 15, d = r;

    // ---- prefetch ALL tile metadata before the barrier (overlaps stage HBM) ----
    // js[tile][s]: LDS byte addr of neighbor row for kslot s*4+g (sentinel if padded).
    // smask lo/hi: 4 site bits per tile (rows g*4+0..3), tiles 0..7 / 8..15.
    uint32_t js[16][3];
    uint32_t smask_lo = 0, smask_hi = 0;
    #pragma unroll
    for (int tile = 0; tile < 16; ++tile) {
        const int n0 = wv * 256 + tile * 16;
        #pragma unroll
        for (int s = 0; s < 3; ++s) {
            const int ks = s * 4 + g;
            const int j = (ks < KNB) ? nbh[(n0 + r) * KNB + ks] : NSZ;
            js[tile][s] = (uint32_t)j << 4;
        }
        const int4 sv = *reinterpret_cast<const int4*>(sub + n0 + g * 4);
        const uint32_t bits = (uint32_t)((sv.x & 1) | ((sv.y & 1) << 1) |
                                         ((sv.z & 1) << 2) | ((sv.w & 1) << 3));
        if (tile < 8) smask_lo |= bits << (4 * tile);
        else          smask_hi |= bits << (4 * (tile - 8));
    }

    const float bz0 = bias[d & 7];
    const float bz1 = bias[DOUT + (d & 7)];

    __syncthreads();

    // B-fragments: 2 sites x 3 K-steps, resident in 24 VGPRs for the whole kernel
    u32x4 bf[2][3];
    #pragma unroll
    for (int sg = 0; sg < 2; ++sg)
        #pragma unroll
        for (int s = 0; s < 3; ++s)
            bf[sg][s] = *reinterpret_cast<const u32x4*>(
                &xl[BOFF + 4 * (size_t)((sg * 3 + s) * 64 + lane)]);

    const char* xlb = reinterpret_cast<const char*>(xl);
    #pragma unroll
    for (int tile = 0; tile < 16; ++tile) {
        const int n0 = wv * 256 + tile * 16;

        f4 a0 = { 0.f, 0.f, 0.f, 0.f };
        f4 a1 = { 0.f, 0.f, 0.f, 0.f };
        #pragma unroll
        for (int s = 0; s < 3; ++s) {
            const u32x4 av = *reinterpret_cast<const u32x4*>(xlb + js[tile][s]);
            const v8fh af = __builtin_bit_cast(v8fh, av);
            a0 = __builtin_amdgcn_mfma_f32_16x16x32_f16(af, __builtin_bit_cast(v8fh, bf[0][s]), a0, 0, 0, 0);
            a1 = __builtin_amdgcn_mfma_f32_16x16x32_f16(af, __builtin_bit_cast(v8fh, bf[1][s]), a1, 0, 0, 0);
        }

        if (d < DOUT) {   // cols 8..15 are padding
            const uint32_t bits = (tile < 8) ? (smask_lo >> (4 * tile))
                                             : (smask_hi >> (4 * (tile - 8)));
            f4 o;
            #pragma unroll
            for (int reg = 0; reg < 4; ++reg) {
                const bool s1 = (bits >> reg) & 1;
                o[reg] = (s1 ? a1[reg] : a0[reg]) + (s1 ? bz1 : bz0);
            }
            // rows g*4+reg are 4 consecutive n -> 16B store; lanes g=0..3 tile a 64B line
            *reinterpret_cast<f4*>(out + ((size_t)b * DOUT + d) * NSZ + n0 + g * 4) = o;
        }
    }
}

extern "C" void kernel_launch(void* const* d_in, const int* in_sizes, int n_in,
                              void* d_out, int out_size, void* d_ws, size_t ws_size,
                              hipStream_t stream) {
    const float* x    = (const float*)d_in[0];
    const int*   nbh  = (const int*)d_in[1];
    const int*   sub  = (const int*)d_in[2];
    const float* w    = (const float*)d_in[3];
    const float* bias = (const float*)d_in[4];
    float* out = (float*)d_out;
    (void)d_ws; (void)ws_size;

    latconv_kernel<<<BSZ, 1024, 0, stream>>>(x, nbh, sub, w, bias, out);
}

// Round 9
// 102.280 us; speedup vs baseline: 1.0713x; 1.0713x over previous
//
#include <hip/hip_runtime.h>
#include <stdint.h>
#include <stddef.h>

// Problem constants (fixed by the reference).
#define BSZ  256
#define NSZ  4096
#define CIN  8
#define KNB  9
#define DOUT 8
#define NSUB 2

typedef __fp16   fh2  __attribute__((ext_vector_type(2)));
typedef __fp16   v8fh __attribute__((ext_vector_type(8)));   // MFMA f16 A/B frag (4 VGPRs)
typedef float    f4   __attribute__((ext_vector_type(4)));
typedef uint32_t u32x4 __attribute__((ext_vector_type(4)));

#define BTAB_U32 (NSUB * 3 * 64 * 4)          // 1536 u32 = 6 KiB
#define BOFF     ((NSZ + 1) * 4)              // btab offset (u32 units) in LDS

static __device__ __forceinline__ uint32_t pk_f16(float a, float b) {
    fh2 h = __builtin_amdgcn_cvt_pkrtz(a, b);   // v_cvt_pkrtz_f16_f32
    return __builtin_bit_cast(uint32_t, h);
}

// grid = 512: b = bid&255, half = bid>>8 (R7 structure — measured best, 101.6).
// __launch_bounds__(1024,8): VGPR<=64 so LDS (71.7KB) is the limiter -> 2 blocks/CU.
// Per 16-n tile: 3 gathered ds_read_b128 A-frags, 6 MFMAs (2 sites x K=96).
// NEW vs R7: next-tile metadata (3 nbh addrs + 4 site bits) double-buffered so its
// L2 latency hides under the current tile's MFMAs.
__global__ __launch_bounds__(1024, 8) void latconv_kernel(
    const float* __restrict__ x, const int* __restrict__ nbh,
    const int* __restrict__ sub, const float* __restrict__ w,
    const float* __restrict__ bias, float* __restrict__ out)
{
    __shared__ __align__(16) uint32_t xl[BOFF + BTAB_U32];   // 65552 + 6144 B

    const int b    = blockIdx.x & 255;
    const int half = blockIdx.x >> 8;
    const int t    = threadIdx.x;
    const float* xb = x + (size_t)b * (CIN * NSZ);

    // ---- build B-fragment table in LDS ----
    if (t < NSUB * 3 * 64) {
        const int lane2 = t & 63, s = (t >> 6) % 3, sg = t / 192;
        const int g2 = lane2 >> 4, d2 = lane2 & 15, ks = s * 4 + g2;
        u32x4 row;
        #pragma unroll
        for (int cp = 0; cp < 4; ++cp) {
            float v0 = 0.f, v1 = 0.f;
            if (d2 < DOUT && ks < KNB) {
                v0 = w[((sg * CIN + 2 * cp    ) * KNB + ks) * DOUT + d2];
                v1 = w[((sg * CIN + 2 * cp + 1) * KNB + ks) * DOUT + d2];
            }
            row[cp] = pk_f16(v0, v1);
        }
        *reinterpret_cast<u32x4*>(&xl[BOFF + 4 * (size_t)t]) = row;
    }

    // ---- stage x[b] -> LDS (fp32 -> packed fp16, transpose to [j][c]) ----
    {
        const int j0 = 4 * t;
        f4 v[CIN];
        #pragma unroll
        for (int c = 0; c < CIN; ++c)
            v[c] = *reinterpret_cast<const f4*>(xb + c * NSZ + j0);   // coalesced 16B
        #pragma unroll
        for (int jj = 0; jj < 4; ++jj) {
            u32x4 row;
            #pragma unroll
            for (int cp = 0; cp < 4; ++cp)
                row[cp] = pk_f16(v[2 * cp][jj], v[2 * cp + 1][jj]);
            *reinterpret_cast<u32x4*>(&xl[(size_t)(j0 + jj) * 4]) = row;  // ds_write_b128
        }
    }
    if (t == 0) {   // zero sentinel row for padded k-slots
        u32x4 z = { 0, 0, 0, 0 };
        *reinterpret_cast<u32x4*>(&xl[(size_t)NSZ * 4]) = z;
    }

    const int lane = t & 63, wv = t >> 6;
    const int g = lane >> 4, r = lane & 15, d = r;

    const float bz0 = bias[d & 7];
    const float bz1 = bias[DOUT + (d & 7)];

    // metadata loader: 3 LDS byte-addrs (sentinel for padded kslots) + 4 site bits
    const int nbase = half * 2048 + wv * 128;
    auto load_meta = [&](int tile, uint32_t js[3], uint32_t& bits) {
        const int n0 = nbase + tile * 16;
        #pragma unroll
        for (int s = 0; s < 3; ++s) {
            const int ks = s * 4 + g;
            const int j = (ks < KNB) ? nbh[(n0 + r) * KNB + ks] : NSZ;
            js[s] = (uint32_t)j << 4;
        }
        const int4 sv = *reinterpret_cast<const int4*>(sub + n0 + g * 4);
        bits = (uint32_t)((sv.x & 1) | ((sv.y & 1) << 1) |
                          ((sv.z & 1) << 2) | ((sv.w & 1) << 3));
    };

    // prefetch tile 0 metadata (overlaps the staging barrier wait)
    uint32_t jsA[3], bitsA;
    load_meta(0, jsA, bitsA);

    __syncthreads();

    // B-fragments: 2 sites x 3 K-steps, resident in 24 VGPRs
    u32x4 bf[2][3];
    #pragma unroll
    for (int sg = 0; sg < 2; ++sg)
        #pragma unroll
        for (int s = 0; s < 3; ++s)
            bf[sg][s] = *reinterpret_cast<const u32x4*>(
                &xl[BOFF + 4 * (size_t)((sg * 3 + s) * 64 + lane)]);

    const char* xlb = reinterpret_cast<const char*>(xl);
    #pragma unroll
    for (int tile = 0; tile < 8; ++tile) {
        // issue next tile's metadata loads before this tile's MFMAs (latency hiding)
        uint32_t jsB[3], bitsB;
        if (tile < 7) load_meta(tile + 1, jsB, bitsB);

        f4 a0 = { 0.f, 0.f, 0.f, 0.f };
        f4 a1 = { 0.f, 0.f, 0.f, 0.f };
        #pragma unroll
        for (int s = 0; s < 3; ++s) {
            const u32x4 av = *reinterpret_cast<const u32x4*>(xlb + jsA[s]);
            const v8fh af = __builtin_bit_cast(v8fh, av);
            a0 = __builtin_amdgcn_mfma_f32_16x16x32_f16(af, __builtin_bit_cast(v8fh, bf[0][s]), a0, 0, 0, 0);
            a1 = __builtin_amdgcn_mfma_f32_16x16x32_f16(af, __builtin_bit_cast(v8fh, bf[1][s]), a1, 0, 0, 0);
        }

        if (d < DOUT) {   // cols 8..15 are padding
            const int n0 = nbase + tile * 16;
            f4 o;
            #pragma unroll
            for (int reg = 0; reg < 4; ++reg) {
                const bool s1 = (bitsA >> reg) & 1;
                o[reg] = (s1 ? a1[reg] : a0[reg]) + (s1 ? bz1 : bz0);
            }
            // rows g*4+reg are 4 consecutive n -> 16B store; lanes g=0..3 tile a 64B line
            *reinterpret_cast<f4*>(out + ((size_t)b * DOUT + d) * NSZ + n0 + g * 4) = o;
        }

        #pragma unroll
        for (int s = 0; s < 3; ++s) jsA[s] = jsB[s];
        bitsA = bitsB;
    }
}

extern "C" void kernel_launch(void* const* d_in, const int* in_sizes, int n_in,
                              void* d_out, int out_size, void* d_ws, size_t ws_size,
                              hipStream_t stream) {
    const float* x    = (const float*)d_in[0];
    const int*   nbh  = (const int*)d_in[1];
    const int*   sub  = (const int*)d_in[2];
    const float* w    = (const float*)d_in[3];
    const float* bias = (const float*)d_in[4];
    float* out = (float*)d_out;
    (void)d_ws; (void)ws_size;

    latconv_kernel<<<2 * BSZ, 1024, 0, stream>>>(x, nbh, sub, w, bias, out);
}